// Round 17
// baseline (63.093 us; speedup 1.0000x reference)
//
#include <hip/hip_runtime.h>

#define N_   32
#define C_   3
#define T_   300
#define V_   25
#define OUT_ 96
#define ROWP 28              // padded row (float4-aligned)
#define NCH  60              // partial records per n (15 chunks x 4 waves)
#define TT2  20              // t's per k_out block (500 j per block)
#define OH   48              // o's per k_out block (o-split: 2 halves)
#define SEL  (3*V_*V_)       // 1875 floats per sum record

using half8   = __attribute__((ext_vector_type(8))) _Float16;
using floatx4 = __attribute__((ext_vector_type(4))) float;

// ---------------------------------------------------------------------------
// K1 (MFMA): round-11/13 version byte-identical. Measured: 14.2us (r14).
// ---------------------------------------------------------------------------
__global__ __launch_bounds__(256) void k_powsum(const float* __restrict__ xx,
                                                float* __restrict__ partial) {
    const int n = blockIdx.x, chunk = blockIdx.y;   // 15 chunks x 20 t
    const int tid  = threadIdx.x;
    const int wid  = tid >> 6;
    const int lane = tid & 63;
    const int r0   = lane & 15;
    const int kb   = (lane >> 4) * 8;

    __shared__ __align__(16) float xst[4][3][32];
    __shared__ __align__(16) float a2b[4][32][36];

    half8 I0 = {}, I1 = {};
    #pragma unroll
    for (int j = 0; j < 8; ++j) {
        if (kb + j == r0)      I0[j] = (_Float16)1.0f;
        if (kb + j == 16 + r0) I1[j] = (_Float16)1.0f;
    }

    floatx4 acc[3][4];
    #pragma unroll
    for (int s = 0; s < 3; ++s)
        #pragma unroll
        for (int q = 0; q < 4; ++q)
            #pragma unroll
            for (int r = 0; r < 4; ++r) acc[s][q][r] = 0.f;

    const float* xxn = xx + (size_t)n * C_*T_*V_;
    const bool rowOK1 = (r0 < 9);

    for (int tt = 0; tt < 5; ++tt) {
        const int t = chunk*20 + wid*5 + tt;
        {
            const int i0 = lane;
            if (i0 < 75) xst[wid][i0/25][i0%25] = xxn[(i0/25)*(T_*V_) + t*V_ + (i0%25)];
            const int i1 = 64 + lane;
            if (lane < 11) xst[wid][i1/25][i1%25] = xxn[(i1/25)*(T_*V_) + t*V_ + (i1%25)];
        }
        __syncthreads();

        float xr0c[3], xr1c[3], xk[3][8];
        #pragma unroll
        for (int c = 0; c < 3; ++c) {
            xr0c[c] = xst[wid][c][r0];
            xr1c[c] = xst[wid][c][16 + r0];
            const float4 k0 = *(const float4*)&xst[wid][c][kb];
            const float4 k1 = *(const float4*)&xst[wid][c][kb + 4];
            xk[c][0]=k0.x; xk[c][1]=k0.y; xk[c][2]=k0.z; xk[c][3]=k0.w;
            xk[c][4]=k1.x; xk[c][5]=k1.y; xk[c][6]=k1.z; xk[c][7]=k1.w;
        }
        half8 F0, F1;
        #pragma unroll
        for (int j = 0; j < 8; ++j) {
            const int  kk  = kb + j;
            const bool kOK = (kk < 25);
            float d0 = xr0c[0]-xk[0][j], d1 = xr0c[1]-xk[1][j], d2 = xr0c[2]-xk[2][j];
            const float a0 = __expf(-(d0*d0 + d1*d1 + d2*d2));
            F0[j] = kOK ? (_Float16)a0 : (_Float16)0.f;
            float e0 = xr1c[0]-xk[0][j], e1 = xr1c[1]-xk[1][j], e2 = xr1c[2]-xk[2][j];
            const float a1 = __expf(-(e0*e0 + e1*e1 + e2*e2));
            F1[j] = (kOK && rowOK1) ? (_Float16)a1 : (_Float16)0.f;
        }

        const floatx4 z = {0.f, 0.f, 0.f, 0.f};
        floatx4 d2q[4];
        d2q[0] = __builtin_amdgcn_mfma_f32_16x16x32_f16(F0, F0, z, 0, 0, 0);
        d2q[1] = __builtin_amdgcn_mfma_f32_16x16x32_f16(F0, F1, z, 0, 0, 0);
        d2q[2] = __builtin_amdgcn_mfma_f32_16x16x32_f16(F1, F0, z, 0, 0, 0);
        d2q[3] = __builtin_amdgcn_mfma_f32_16x16x32_f16(F1, F1, z, 0, 0, 0);
        acc[0][0] = __builtin_amdgcn_mfma_f32_16x16x32_f16(I0, F0, acc[0][0], 0, 0, 0);
        acc[0][1] = __builtin_amdgcn_mfma_f32_16x16x32_f16(I0, F1, acc[0][1], 0, 0, 0);
        acc[0][2] = __builtin_amdgcn_mfma_f32_16x16x32_f16(I1, F0, acc[0][2], 0, 0, 0);
        acc[0][3] = __builtin_amdgcn_mfma_f32_16x16x32_f16(I1, F1, acc[0][3], 0, 0, 0);
        const int rbase = (lane >> 4) * 4;
        #pragma unroll
        for (int q = 0; q < 4; ++q) {
            #pragma unroll
            for (int r = 0; r < 4; ++r) acc[1][q][r] += d2q[q][r];
            const int RB = 16*(q>>1) + rbase, CC = 16*(q&1) + r0;
            #pragma unroll
            for (int r = 0; r < 4; ++r) a2b[wid][RB + r][CC] = d2q[q][r];
        }
        __syncthreads();

        const float4 m0 = *(const float4*)&a2b[wid][r0][kb];
        const float4 m1 = *(const float4*)&a2b[wid][r0][kb + 4];
        const float4 m2 = *(const float4*)&a2b[wid][16 + r0][kb];
        const float4 m3 = *(const float4*)&a2b[wid][16 + r0][kb + 4];
        half8 FA0, FA1;
        FA0[0]=(_Float16)m0.x; FA0[1]=(_Float16)m0.y; FA0[2]=(_Float16)m0.z; FA0[3]=(_Float16)m0.w;
        FA0[4]=(_Float16)m1.x; FA0[5]=(_Float16)m1.y; FA0[6]=(_Float16)m1.z; FA0[7]=(_Float16)m1.w;
        FA1[0]=(_Float16)m2.x; FA1[1]=(_Float16)m2.y; FA1[2]=(_Float16)m2.z; FA1[3]=(_Float16)m2.w;
        FA1[4]=(_Float16)m3.x; FA1[5]=(_Float16)m3.y; FA1[6]=(_Float16)m3.z; FA1[7]=(_Float16)m3.w;
        acc[2][0] = __builtin_amdgcn_mfma_f32_16x16x32_f16(FA0, F0, acc[2][0], 0, 0, 0);
        acc[2][1] = __builtin_amdgcn_mfma_f32_16x16x32_f16(FA0, F1, acc[2][1], 0, 0, 0);
        acc[2][2] = __builtin_amdgcn_mfma_f32_16x16x32_f16(FA1, F0, acc[2][2], 0, 0, 0);
        acc[2][3] = __builtin_amdgcn_mfma_f32_16x16x32_f16(FA1, F1, acc[2][3], 0, 0, 0);
        __syncthreads();
    }

    float* pb = partial + ((size_t)n*NCH + chunk*4 + wid) * SEL;
    const int rbase = (lane >> 4) * 4;
    #pragma unroll
    for (int s = 0; s < 3; ++s) {
        #pragma unroll
        for (int q = 0; q < 4; ++q) {
            const int RB = 16*(q>>1) + rbase, CC = 16*(q&1) + r0;
            #pragma unroll
            for (int r = 0; r < 4; ++r) a2b[wid][RB + r][CC] = acc[s][q][r];
        }
        __syncthreads();
        for (int i = lane; i < V_*V_; i += 64)
            pb[s*V_*V_ + i] = a2b[wid][i/V_][i%V_];
        __syncthreads();
    }
}

// ---------------------------------------------------------------------------
// K1b: byte-identical r13.
// ---------------------------------------------------------------------------
__global__ __launch_bounds__(256) void k_reduce(const float* __restrict__ partial,
                                                float* __restrict__ Ssum) {
    const int g = blockIdx.x*256 + threadIdx.x;
    if (g >= N_*SEL) return;
    const int n = g / SEL, j = g % SEL;
    const float* p = partial + (size_t)n*NCH*SEL + j;
    float s = 0.f;
    #pragma unroll
    for (int c = 0; c < NCH; ++c) s += p[(size_t)c*SEL];
    Ssum[g] = s;
}

// ---------------------------------------------------------------------------
// K2 v13: r13 j-pair structure, but the o-dimension is SPLIT across 2 blocks
// (blockIdx.z = o-half, 48 o's each) -> 960 blocks = 3.75/CU (~15 waves/CU)
// so the LDS / VALU / store streams of co-resident waves overlap instead of
// summing (r13's 1.875 blocks/CU ran them back-to-back). Per-output FMA
// order unchanged -> bit-identical results. Wl stages only this half's rows.
// ---------------------------------------------------------------------------
__global__ __launch_bounds__(256) void k_out(const float* __restrict__ x,
                                             const float* __restrict__ Ssum,
                                             const float* __restrict__ W,
                                             const float* __restrict__ b,
                                             const float* __restrict__ gamma,
                                             const float* __restrict__ beta,
                                             float* __restrict__ out) {
    const int n = blockIdx.x, tile = blockIdx.y;  // 15 tiles x 20 t
    const int o0 = blockIdx.z * OH;               // o-half base
    const int tid = threadIdx.x;

    __shared__ __align__(16) float S_l[3*V_*ROWP];     // 2100
    __shared__ __align__(16) float xsh[TT2*C_*ROWP];   // 1680
    __shared__ __align__(16) float Wl[OH*12];          // 576
    __shared__ __align__(8)  float2 so[OH];            // (scl, off)

    const float* xn = x + (size_t)n * C_*T_*V_;
    const int t0 = tile * TT2;
    const float inv_bn = rsqrtf(1.0f + 1e-5f);

    for (int i = tid; i < 3*V_*ROWP; i += 256) {
        const int s = i/(V_*ROWP), r = i%(V_*ROWP), v = r/ROWP, u = r%ROWP;
        S_l[i] = (u < V_) ? Ssum[(size_t)n*SEL + s*V_*V_ + v*V_ + u] : 0.f;
    }
    for (int i = tid; i < TT2*C_*ROWP; i += 256) {
        const int tt = i/(C_*ROWP), r = i%(C_*ROWP), c = r/ROWP, u = r%ROWP;
        xsh[i] = (u < V_) ? xn[c*(T_*V_) + (t0+tt)*V_ + u] : 0.f;
    }
    for (int i = tid; i < OH*12; i += 256) Wl[i] = W[o0*12 + i];
    if (tid < OH) {
        const int o = o0 + tid;
        const float sc = gamma[o] * inv_bn;
        so[tid] = make_float2(sc, b[o]*sc + beta[o]);
    }
    __syncthreads();

    if (tid < TT2*V_/2) {
        const int j0 = 2*tid, j1 = 2*tid + 1;
        const int tt0 = j0 / V_, iv0 = j0 % V_;
        const int tt1 = j1 / V_, iv1 = j1 % V_;
        const float* xb0 = &xsh[tt0*C_*ROWP];
        const float* xb1 = &xsh[tt1*C_*ROWP];

        float agg0[12], agg1[12];
        agg0[0] = (float)T_ * xb0[0*ROWP + iv0];
        agg0[1] = (float)T_ * xb0[1*ROWP + iv0];
        agg0[2] = (float)T_ * xb0[2*ROWP + iv0];
        agg1[0] = (float)T_ * xb1[0*ROWP + iv1];
        agg1[1] = (float)T_ * xb1[1*ROWP + iv1];
        agg1[2] = (float)T_ * xb1[2*ROWP + iv1];
        #pragma unroll
        for (int k = 3; k < 12; ++k) { agg0[k] = 0.f; agg1[k] = 0.f; }

        const float* Sr[3] = { &S_l[0*V_*ROWP], &S_l[1*V_*ROWP], &S_l[2*V_*ROWP] };
        #pragma unroll
        for (int u4 = 0; u4 < ROWP; u4 += 4) {
            const float4 p0 = *(const float4*)&xb0[0*ROWP + u4];
            const float4 p1 = *(const float4*)&xb0[1*ROWP + u4];
            const float4 p2 = *(const float4*)&xb0[2*ROWP + u4];
            const float4 q0 = *(const float4*)&xb1[0*ROWP + u4];
            const float4 q1 = *(const float4*)&xb1[1*ROWP + u4];
            const float4 q2 = *(const float4*)&xb1[2*ROWP + u4];
            #pragma unroll
            for (int s = 0; s < 3; ++s) {
                const float4 sa = *(const float4*)&Sr[s][iv0*ROWP + u4];
                const float4 sb = *(const float4*)&Sr[s][iv1*ROWP + u4];
                agg0[3*s+3] += sa.x*p0.x + sa.y*p0.y + sa.z*p0.z + sa.w*p0.w;
                agg0[3*s+4] += sa.x*p1.x + sa.y*p1.y + sa.z*p1.z + sa.w*p1.w;
                agg0[3*s+5] += sa.x*p2.x + sa.y*p2.y + sa.z*p2.z + sa.w*p2.w;
                agg1[3*s+3] += sb.x*q0.x + sb.y*q0.y + sb.z*q0.z + sb.w*q0.w;
                agg1[3*s+4] += sb.x*q1.x + sb.y*q1.y + sb.z*q1.z + sb.w*q1.w;
                agg1[3*s+5] += sb.x*q2.x + sb.y*q2.y + sb.z*q2.z + sb.w*q2.w;
            }
        }

        float* on = out + (size_t)n*(size_t)OUT_*T_*V_ + (size_t)o0*(T_*V_) + t0*V_ + j0;
        #pragma unroll 4
        for (int ol = 0; ol < OH; ++ol) {
            const float4 w0 = *(const float4*)&Wl[ol*12];
            const float4 w1 = *(const float4*)&Wl[ol*12+4];
            const float4 w2 = *(const float4*)&Wl[ol*12+8];
            const float2 s2 = so[ol];
            float a0 = w0.x*agg0[0] + w0.y*agg0[1] + w0.z*agg0[2] + w0.w*agg0[3]
                     + w1.x*agg0[4] + w1.y*agg0[5] + w1.z*agg0[6] + w1.w*agg0[7]
                     + w2.x*agg0[8] + w2.y*agg0[9] + w2.z*agg0[10]+ w2.w*agg0[11];
            float a1 = w0.x*agg1[0] + w0.y*agg1[1] + w0.z*agg1[2] + w0.w*agg1[3]
                     + w1.x*agg1[4] + w1.y*agg1[5] + w1.z*agg1[6] + w1.w*agg1[7]
                     + w2.x*agg1[8] + w2.y*agg1[9] + w2.z*agg1[10]+ w2.w*agg1[11];
            float2 r;
            r.x = fmaxf(a0*s2.x + s2.y, 0.f);
            r.y = fmaxf(a1*s2.x + s2.y, 0.f);
            *(float2*)&on[(size_t)ol*(T_*V_)] = r;
        }
    }
}

extern "C" void kernel_launch(void* const* d_in, const int* in_sizes, int n_in,
                              void* d_out, int out_size, void* d_ws, size_t ws_size,
                              hipStream_t stream) {
    const float* x     = (const float*)d_in[0];
    const float* xx    = (const float*)d_in[1];
    const float* W     = (const float*)d_in[2];
    const float* b     = (const float*)d_in[3];
    const float* gamma = (const float*)d_in[4];
    const float* beta  = (const float*)d_in[5];
    float* out  = (float*)d_out;

    float* Ssum    = (float*)d_ws;                  // 240 KB
    float* partial = (float*)d_ws + (size_t)N_*SEL; // 14.4 MB (60 recs/n)

    k_powsum<<<dim3(N_, 15), 256, 0, stream>>>(xx, partial);
    k_reduce<<<(N_*SEL + 255)/256, 256, 0, stream>>>(partial, Ssum);
    k_out   <<<dim3(N_, T_/TT2, OUT_/OH), 256, 0, stream>>>(x, Ssum, W, b, gamma, beta, out);
}

// Round 18
// 56.351 us; speedup vs baseline: 1.1196x; 1.1196x over previous
//
#include <hip/hip_runtime.h>

#define N_   32
#define C_   3
#define T_   300
#define V_   25
#define OUT_ 96
#define ROWP 28              // padded row (float4-aligned)
#define NCH  60              // partial records per n (15 chunks x 4 waves)
#define TT2  20              // t's per k_out block (500 j per block)
#define SEL  (3*V_*V_)       // 1875 floats per sum record

using half8   = __attribute__((ext_vector_type(8))) _Float16;
using floatx4 = __attribute__((ext_vector_type(4))) float;

// ---------------------------------------------------------------------------
// K1 (MFMA): r13 kernel with ALL __syncthreads REMOVED — every LDS buffer
// (xst[wid], a2b[wid]) is wave-private, and cross-lane traffic WITHIN a wave
// is ordered by wave-lockstep + in-order LDS pipe + compiler lgkmcnt. The 16
// block-wide barriers per block (2/t x 5t + 6 epilogue) were pure 4-wave
// lockstep waste (each also force-drains vmcnt/lgkmcnt). Single-variable
// change vs r13 (r12 confounded this with 3 other changes).
// ---------------------------------------------------------------------------
__global__ __launch_bounds__(256) void k_powsum(const float* __restrict__ xx,
                                                float* __restrict__ partial) {
    const int n = blockIdx.x, chunk = blockIdx.y;   // 15 chunks x 20 t
    const int tid  = threadIdx.x;
    const int wid  = tid >> 6;
    const int lane = tid & 63;
    const int r0   = lane & 15;
    const int kb   = (lane >> 4) * 8;

    __shared__ __align__(16) float xst[4][3][32];    // wave-private
    __shared__ __align__(16) float a2b[4][32][36];   // wave-private

    half8 I0 = {}, I1 = {};
    #pragma unroll
    for (int j = 0; j < 8; ++j) {
        if (kb + j == r0)      I0[j] = (_Float16)1.0f;
        if (kb + j == 16 + r0) I1[j] = (_Float16)1.0f;
    }

    floatx4 acc[3][4];
    #pragma unroll
    for (int s = 0; s < 3; ++s)
        #pragma unroll
        for (int q = 0; q < 4; ++q)
            #pragma unroll
            for (int r = 0; r < 4; ++r) acc[s][q][r] = 0.f;

    const float* xxn = xx + (size_t)n * C_*T_*V_;
    const bool rowOK1 = (r0 < 9);

    for (int tt = 0; tt < 5; ++tt) {
        const int t = chunk*20 + wid*5 + tt;
        {
            const int i0 = lane;
            if (i0 < 75) xst[wid][i0/25][i0%25] = xxn[(i0/25)*(T_*V_) + t*V_ + (i0%25)];
            const int i1 = 64 + lane;
            if (lane < 11) xst[wid][i1/25][i1%25] = xxn[(i1/25)*(T_*V_) + t*V_ + (i1%25)];
        }
        // (no barrier: wave-private LDS, within-wave cross-lane is in-order)

        float xr0c[3], xr1c[3], xk[3][8];
        #pragma unroll
        for (int c = 0; c < 3; ++c) {
            xr0c[c] = xst[wid][c][r0];
            xr1c[c] = xst[wid][c][16 + r0];
            const float4 k0 = *(const float4*)&xst[wid][c][kb];
            const float4 k1 = *(const float4*)&xst[wid][c][kb + 4];
            xk[c][0]=k0.x; xk[c][1]=k0.y; xk[c][2]=k0.z; xk[c][3]=k0.w;
            xk[c][4]=k1.x; xk[c][5]=k1.y; xk[c][6]=k1.z; xk[c][7]=k1.w;
        }
        half8 F0, F1;
        #pragma unroll
        for (int j = 0; j < 8; ++j) {
            const int  kk  = kb + j;
            const bool kOK = (kk < 25);
            float d0 = xr0c[0]-xk[0][j], d1 = xr0c[1]-xk[1][j], d2 = xr0c[2]-xk[2][j];
            const float a0 = __expf(-(d0*d0 + d1*d1 + d2*d2));
            F0[j] = kOK ? (_Float16)a0 : (_Float16)0.f;
            float e0 = xr1c[0]-xk[0][j], e1 = xr1c[1]-xk[1][j], e2 = xr1c[2]-xk[2][j];
            const float a1 = __expf(-(e0*e0 + e1*e1 + e2*e2));
            F1[j] = (kOK && rowOK1) ? (_Float16)a1 : (_Float16)0.f;
        }

        const floatx4 z = {0.f, 0.f, 0.f, 0.f};
        floatx4 d2q[4];
        d2q[0] = __builtin_amdgcn_mfma_f32_16x16x32_f16(F0, F0, z, 0, 0, 0);
        d2q[1] = __builtin_amdgcn_mfma_f32_16x16x32_f16(F0, F1, z, 0, 0, 0);
        d2q[2] = __builtin_amdgcn_mfma_f32_16x16x32_f16(F1, F0, z, 0, 0, 0);
        d2q[3] = __builtin_amdgcn_mfma_f32_16x16x32_f16(F1, F1, z, 0, 0, 0);
        acc[0][0] = __builtin_amdgcn_mfma_f32_16x16x32_f16(I0, F0, acc[0][0], 0, 0, 0);
        acc[0][1] = __builtin_amdgcn_mfma_f32_16x16x32_f16(I0, F1, acc[0][1], 0, 0, 0);
        acc[0][2] = __builtin_amdgcn_mfma_f32_16x16x32_f16(I1, F0, acc[0][2], 0, 0, 0);
        acc[0][3] = __builtin_amdgcn_mfma_f32_16x16x32_f16(I1, F1, acc[0][3], 0, 0, 0);
        const int rbase = (lane >> 4) * 4;
        #pragma unroll
        for (int q = 0; q < 4; ++q) {
            #pragma unroll
            for (int r = 0; r < 4; ++r) acc[1][q][r] += d2q[q][r];
            const int RB = 16*(q>>1) + rbase, CC = 16*(q&1) + r0;
            #pragma unroll
            for (int r = 0; r < 4; ++r) a2b[wid][RB + r][CC] = d2q[q][r];
        }
        // (no barrier)

        const float4 m0 = *(const float4*)&a2b[wid][r0][kb];
        const float4 m1 = *(const float4*)&a2b[wid][r0][kb + 4];
        const float4 m2 = *(const float4*)&a2b[wid][16 + r0][kb];
        const float4 m3 = *(const float4*)&a2b[wid][16 + r0][kb + 4];
        half8 FA0, FA1;
        FA0[0]=(_Float16)m0.x; FA0[1]=(_Float16)m0.y; FA0[2]=(_Float16)m0.z; FA0[3]=(_Float16)m0.w;
        FA0[4]=(_Float16)m1.x; FA0[5]=(_Float16)m1.y; FA0[6]=(_Float16)m1.z; FA0[7]=(_Float16)m1.w;
        FA1[0]=(_Float16)m2.x; FA1[1]=(_Float16)m2.y; FA1[2]=(_Float16)m2.z; FA1[3]=(_Float16)m2.w;
        FA1[4]=(_Float16)m3.x; FA1[5]=(_Float16)m3.y; FA1[6]=(_Float16)m3.z; FA1[7]=(_Float16)m3.w;
        acc[2][0] = __builtin_amdgcn_mfma_f32_16x16x32_f16(FA0, F0, acc[2][0], 0, 0, 0);
        acc[2][1] = __builtin_amdgcn_mfma_f32_16x16x32_f16(FA0, F1, acc[2][1], 0, 0, 0);
        acc[2][2] = __builtin_amdgcn_mfma_f32_16x16x32_f16(FA1, F0, acc[2][2], 0, 0, 0);
        acc[2][3] = __builtin_amdgcn_mfma_f32_16x16x32_f16(FA1, F1, acc[2][3], 0, 0, 0);
        // (no barrier: next tt's xst/a2b writes are same-wave, in-order)
    }

    float* pb = partial + ((size_t)n*NCH + chunk*4 + wid) * SEL;
    const int rbase = (lane >> 4) * 4;
    #pragma unroll
    for (int s = 0; s < 3; ++s) {
        #pragma unroll
        for (int q = 0; q < 4; ++q) {
            const int RB = 16*(q>>1) + rbase, CC = 16*(q&1) + r0;
            #pragma unroll
            for (int r = 0; r < 4; ++r) a2b[wid][RB + r][CC] = acc[s][q][r];
        }
        // (no barrier: same-wave scatter->coalesced-read, in-order)
        for (int i = lane; i < V_*V_; i += 64)
            pb[s*V_*V_ + i] = a2b[wid][i/V_][i%V_];
        // (no barrier: next s's writes are same-wave after these reads)
    }
}

// ---------------------------------------------------------------------------
// K1b: byte-identical r13.
// ---------------------------------------------------------------------------
__global__ __launch_bounds__(256) void k_reduce(const float* __restrict__ partial,
                                                float* __restrict__ Ssum) {
    const int g = blockIdx.x*256 + threadIdx.x;
    if (g >= N_*SEL) return;
    const int n = g / SEL, j = g % SEL;
    const float* p = partial + (size_t)n*NCH*SEL + j;
    float s = 0.f;
    #pragma unroll
    for (int c = 0; c < NCH; ++c) s += p[(size_t)c*SEL];
    Ssum[g] = s;
}

// ---------------------------------------------------------------------------
// K2 v10: byte-identical r13 (j-pair, float2 stores; O ~= 27us).
// ---------------------------------------------------------------------------
__global__ __launch_bounds__(256) void k_out(const float* __restrict__ x,
                                             const float* __restrict__ Ssum,
                                             const float* __restrict__ W,
                                             const float* __restrict__ b,
                                             const float* __restrict__ gamma,
                                             const float* __restrict__ beta,
                                             float* __restrict__ out) {
    const int n = blockIdx.x, tile = blockIdx.y;  // 15 tiles x 20 t
    const int tid = threadIdx.x;

    __shared__ __align__(16) float S_l[3*V_*ROWP];     // 2100
    __shared__ __align__(16) float xsh[TT2*C_*ROWP];   // 1680
    __shared__ __align__(16) float Wl[OUT_*12];        // 1152
    __shared__ __align__(8)  float2 so[OUT_];          // (scl, off) packed

    const float* xn = x + (size_t)n * C_*T_*V_;
    const int t0 = tile * TT2;
    const float inv_bn = rsqrtf(1.0f + 1e-5f);

    for (int i = tid; i < 3*V_*ROWP; i += 256) {
        const int s = i/(V_*ROWP), r = i%(V_*ROWP), v = r/ROWP, u = r%ROWP;
        S_l[i] = (u < V_) ? Ssum[(size_t)n*SEL + s*V_*V_ + v*V_ + u] : 0.f;
    }
    for (int i = tid; i < TT2*C_*ROWP; i += 256) {
        const int tt = i/(C_*ROWP), r = i%(C_*ROWP), c = r/ROWP, u = r%ROWP;
        xsh[i] = (u < V_) ? xn[c*(T_*V_) + (t0+tt)*V_ + u] : 0.f;
    }
    for (int i = tid; i < OUT_*12; i += 256) Wl[i] = W[i];
    if (tid < OUT_) {
        const float sc = gamma[tid] * inv_bn;
        so[tid] = make_float2(sc, b[tid]*sc + beta[tid]);
    }
    __syncthreads();

    if (tid < TT2*V_/2) {
        const int j0 = 2*tid, j1 = 2*tid + 1;
        const int tt0 = j0 / V_, iv0 = j0 % V_;
        const int tt1 = j1 / V_, iv1 = j1 % V_;
        const float* xb0 = &xsh[tt0*C_*ROWP];
        const float* xb1 = &xsh[tt1*C_*ROWP];

        float agg0[12], agg1[12];
        agg0[0] = (float)T_ * xb0[0*ROWP + iv0];
        agg0[1] = (float)T_ * xb0[1*ROWP + iv0];
        agg0[2] = (float)T_ * xb0[2*ROWP + iv0];
        agg1[0] = (float)T_ * xb1[0*ROWP + iv1];
        agg1[1] = (float)T_ * xb1[1*ROWP + iv1];
        agg1[2] = (float)T_ * xb1[2*ROWP + iv1];
        #pragma unroll
        for (int k = 3; k < 12; ++k) { agg0[k] = 0.f; agg1[k] = 0.f; }

        const float* Sr[3] = { &S_l[0*V_*ROWP], &S_l[1*V_*ROWP], &S_l[2*V_*ROWP] };
        #pragma unroll
        for (int u4 = 0; u4 < ROWP; u4 += 4) {
            const float4 p0 = *(const float4*)&xb0[0*ROWP + u4];
            const float4 p1 = *(const float4*)&xb0[1*ROWP + u4];
            const float4 p2 = *(const float4*)&xb0[2*ROWP + u4];
            const float4 q0 = *(const float4*)&xb1[0*ROWP + u4];
            const float4 q1 = *(const float4*)&xb1[1*ROWP + u4];
            const float4 q2 = *(const float4*)&xb1[2*ROWP + u4];
            #pragma unroll
            for (int s = 0; s < 3; ++s) {
                const float4 sa = *(const float4*)&Sr[s][iv0*ROWP + u4];
                const float4 sb = *(const float4*)&Sr[s][iv1*ROWP + u4];
                agg0[3*s+3] += sa.x*p0.x + sa.y*p0.y + sa.z*p0.z + sa.w*p0.w;
                agg0[3*s+4] += sa.x*p1.x + sa.y*p1.y + sa.z*p1.z + sa.w*p1.w;
                agg0[3*s+5] += sa.x*p2.x + sa.y*p2.y + sa.z*p2.z + sa.w*p2.w;
                agg1[3*s+3] += sb.x*q0.x + sb.y*q0.y + sb.z*q0.z + sb.w*q0.w;
                agg1[3*s+4] += sb.x*q1.x + sb.y*q1.y + sb.z*q1.z + sb.w*q1.w;
                agg1[3*s+5] += sb.x*q2.x + sb.y*q2.y + sb.z*q2.z + sb.w*q2.w;
            }
        }

        float* on = out + (size_t)n*(size_t)OUT_*T_*V_ + t0*V_ + j0;
        #pragma unroll 4
        for (int o = 0; o < OUT_; ++o) {
            const float4 w0 = *(const float4*)&Wl[o*12];
            const float4 w1 = *(const float4*)&Wl[o*12+4];
            const float4 w2 = *(const float4*)&Wl[o*12+8];
            const float2 s2 = so[o];
            float a0 = w0.x*agg0[0] + w0.y*agg0[1] + w0.z*agg0[2] + w0.w*agg0[3]
                     + w1.x*agg0[4] + w1.y*agg0[5] + w1.z*agg0[6] + w1.w*agg0[7]
                     + w2.x*agg0[8] + w2.y*agg0[9] + w2.z*agg0[10]+ w2.w*agg0[11];
            float a1 = w0.x*agg1[0] + w0.y*agg1[1] + w0.z*agg1[2] + w0.w*agg1[3]
                     + w1.x*agg1[4] + w1.y*agg1[5] + w1.z*agg1[6] + w1.w*agg1[7]
                     + w2.x*agg1[8] + w2.y*agg1[9] + w2.z*agg1[10]+ w2.w*agg1[11];
            float2 r;
            r.x = fmaxf(a0*s2.x + s2.y, 0.f);
            r.y = fmaxf(a1*s2.x + s2.y, 0.f);
            *(float2*)&on[(size_t)o*(T_*V_)] = r;
        }
    }
}

extern "C" void kernel_launch(void* const* d_in, const int* in_sizes, int n_in,
                              void* d_out, int out_size, void* d_ws, size_t ws_size,
                              hipStream_t stream) {
    const float* x     = (const float*)d_in[0];
    const float* xx    = (const float*)d_in[1];
    const float* W     = (const float*)d_in[2];
    const float* b     = (const float*)d_in[3];
    const float* gamma = (const float*)d_in[4];
    const float* beta  = (const float*)d_in[5];
    float* out  = (float*)d_out;

    float* Ssum    = (float*)d_ws;                  // 240 KB
    float* partial = (float*)d_ws + (size_t)N_*SEL; // 14.4 MB (60 recs/n)

    k_powsum<<<dim3(N_, 15), 256, 0, stream>>>(xx, partial);
    k_reduce<<<(N_*SEL + 255)/256, 256, 0, stream>>>(partial, Ssum);
    k_out   <<<dim3(N_, T_/TT2), 256, 0, stream>>>(x, Ssum, W, b, gamma, beta, out);
}

// Round 21
// 56.223 us; speedup vs baseline: 1.1222x; 1.0023x over previous
//
#include <hip/hip_runtime.h>

#define N_   32
#define C_   3
#define T_   300
#define V_   25
#define OUT_ 96
#define ROWP 28              // padded row (float4-aligned)
#define NCH  60              // partial records per n (15 chunks x 4 waves)
#define TT2  20              // t's per k_out block (500 j per block)
#define SEL  (3*V_*V_)       // 1875 floats per sum record

using half8   = __attribute__((ext_vector_type(8))) _Float16;
using floatx4 = __attribute__((ext_vector_type(4))) float;

// ---------------------------------------------------------------------------
// K1 (MFMA, barrier-free): byte-identical r18 (P ~= 13us, replay-stable).
// Wave-private LDS (xst[wid], a2b[wid]); within-wave LDS ordering via
// wave-lockstep + in-order LDS pipe + compiler lgkmcnt. Zero __syncthreads.
// ---------------------------------------------------------------------------
__global__ __launch_bounds__(256) void k_powsum(const float* __restrict__ xx,
                                                float* __restrict__ partial) {
    const int n = blockIdx.x, chunk = blockIdx.y;   // 15 chunks x 20 t
    const int tid  = threadIdx.x;
    const int wid  = tid >> 6;
    const int lane = tid & 63;
    const int r0   = lane & 15;
    const int kb   = (lane >> 4) * 8;

    __shared__ __align__(16) float xst[4][3][32];    // wave-private
    __shared__ __align__(16) float a2b[4][32][36];   // wave-private

    half8 I0 = {}, I1 = {};
    #pragma unroll
    for (int j = 0; j < 8; ++j) {
        if (kb + j == r0)      I0[j] = (_Float16)1.0f;
        if (kb + j == 16 + r0) I1[j] = (_Float16)1.0f;
    }

    floatx4 acc[3][4];
    #pragma unroll
    for (int s = 0; s < 3; ++s)
        #pragma unroll
        for (int q = 0; q < 4; ++q)
            #pragma unroll
            for (int r = 0; r < 4; ++r) acc[s][q][r] = 0.f;

    const float* xxn = xx + (size_t)n * C_*T_*V_;
    const bool rowOK1 = (r0 < 9);

    for (int tt = 0; tt < 5; ++tt) {
        const int t = chunk*20 + wid*5 + tt;
        {
            const int i0 = lane;
            if (i0 < 75) xst[wid][i0/25][i0%25] = xxn[(i0/25)*(T_*V_) + t*V_ + (i0%25)];
            const int i1 = 64 + lane;
            if (lane < 11) xst[wid][i1/25][i1%25] = xxn[(i1/25)*(T_*V_) + t*V_ + (i1%25)];
        }

        float xr0c[3], xr1c[3], xk[3][8];
        #pragma unroll
        for (int c = 0; c < 3; ++c) {
            xr0c[c] = xst[wid][c][r0];
            xr1c[c] = xst[wid][c][16 + r0];
            const float4 k0 = *(const float4*)&xst[wid][c][kb];
            const float4 k1 = *(const float4*)&xst[wid][c][kb + 4];
            xk[c][0]=k0.x; xk[c][1]=k0.y; xk[c][2]=k0.z; xk[c][3]=k0.w;
            xk[c][4]=k1.x; xk[c][5]=k1.y; xk[c][6]=k1.z; xk[c][7]=k1.w;
        }
        half8 F0, F1;
        #pragma unroll
        for (int j = 0; j < 8; ++j) {
            const int  kk  = kb + j;
            const bool kOK = (kk < 25);
            float d0 = xr0c[0]-xk[0][j], d1 = xr0c[1]-xk[1][j], d2 = xr0c[2]-xk[2][j];
            const float a0 = __expf(-(d0*d0 + d1*d1 + d2*d2));
            F0[j] = kOK ? (_Float16)a0 : (_Float16)0.f;
            float e0 = xr1c[0]-xk[0][j], e1 = xr1c[1]-xk[1][j], e2 = xr1c[2]-xk[2][j];
            const float a1 = __expf(-(e0*e0 + e1*e1 + e2*e2));
            F1[j] = (kOK && rowOK1) ? (_Float16)a1 : (_Float16)0.f;
        }

        const floatx4 z = {0.f, 0.f, 0.f, 0.f};
        floatx4 d2q[4];
        d2q[0] = __builtin_amdgcn_mfma_f32_16x16x32_f16(F0, F0, z, 0, 0, 0);
        d2q[1] = __builtin_amdgcn_mfma_f32_16x16x32_f16(F0, F1, z, 0, 0, 0);
        d2q[2] = __builtin_amdgcn_mfma_f32_16x16x32_f16(F1, F0, z, 0, 0, 0);
        d2q[3] = __builtin_amdgcn_mfma_f32_16x16x32_f16(F1, F1, z, 0, 0, 0);
        acc[0][0] = __builtin_amdgcn_mfma_f32_16x16x32_f16(I0, F0, acc[0][0], 0, 0, 0);
        acc[0][1] = __builtin_amdgcn_mfma_f32_16x16x32_f16(I0, F1, acc[0][1], 0, 0, 0);
        acc[0][2] = __builtin_amdgcn_mfma_f32_16x16x32_f16(I1, F0, acc[0][2], 0, 0, 0);
        acc[0][3] = __builtin_amdgcn_mfma_f32_16x16x32_f16(I1, F1, acc[0][3], 0, 0, 0);
        const int rbase = (lane >> 4) * 4;
        #pragma unroll
        for (int q = 0; q < 4; ++q) {
            #pragma unroll
            for (int r = 0; r < 4; ++r) acc[1][q][r] += d2q[q][r];
            const int RB = 16*(q>>1) + rbase, CC = 16*(q&1) + r0;
            #pragma unroll
            for (int r = 0; r < 4; ++r) a2b[wid][RB + r][CC] = d2q[q][r];
        }

        const float4 m0 = *(const float4*)&a2b[wid][r0][kb];
        const float4 m1 = *(const float4*)&a2b[wid][r0][kb + 4];
        const float4 m2 = *(const float4*)&a2b[wid][16 + r0][kb];
        const float4 m3 = *(const float4*)&a2b[wid][16 + r0][kb + 4];
        half8 FA0, FA1;
        FA0[0]=(_Float16)m0.x; FA0[1]=(_Float16)m0.y; FA0[2]=(_Float16)m0.z; FA0[3]=(_Float16)m0.w;
        FA0[4]=(_Float16)m1.x; FA0[5]=(_Float16)m1.y; FA0[6]=(_Float16)m1.z; FA0[7]=(_Float16)m1.w;
        FA1[0]=(_Float16)m2.x; FA1[1]=(_Float16)m2.y; FA1[2]=(_Float16)m2.z; FA1[3]=(_Float16)m2.w;
        FA1[4]=(_Float16)m3.x; FA1[5]=(_Float16)m3.y; FA1[6]=(_Float16)m3.z; FA1[7]=(_Float16)m3.w;
        acc[2][0] = __builtin_amdgcn_mfma_f32_16x16x32_f16(FA0, F0, acc[2][0], 0, 0, 0);
        acc[2][1] = __builtin_amdgcn_mfma_f32_16x16x32_f16(FA0, F1, acc[2][1], 0, 0, 0);
        acc[2][2] = __builtin_amdgcn_mfma_f32_16x16x32_f16(FA1, F0, acc[2][2], 0, 0, 0);
        acc[2][3] = __builtin_amdgcn_mfma_f32_16x16x32_f16(FA1, F1, acc[2][3], 0, 0, 0);
    }

    float* pb = partial + ((size_t)n*NCH + chunk*4 + wid) * SEL;
    const int rbase = (lane >> 4) * 4;
    #pragma unroll
    for (int s = 0; s < 3; ++s) {
        #pragma unroll
        for (int q = 0; q < 4; ++q) {
            const int RB = 16*(q>>1) + rbase, CC = 16*(q&1) + r0;
            #pragma unroll
            for (int r = 0; r < 4; ++r) a2b[wid][RB + r][CC] = acc[s][q][r];
        }
        for (int i = lane; i < V_*V_; i += 64)
            pb[s*V_*V_ + i] = a2b[wid][i/V_][i%V_];
    }
}

// ---------------------------------------------------------------------------
// K1b: byte-identical r13/r18.
// ---------------------------------------------------------------------------
__global__ __launch_bounds__(256) void k_reduce(const float* __restrict__ partial,
                                                float* __restrict__ Ssum) {
    const int g = blockIdx.x*256 + threadIdx.x;
    if (g >= N_*SEL) return;
    const int n = g / SEL, j = g % SEL;
    const float* p = partial + (size_t)n*NCH*SEL + j;
    float s = 0.f;
    #pragma unroll
    for (int c = 0; c < NCH; ++c) s += p[(size_t)c*SEL];
    Ssum[g] = s;
}

// ---------------------------------------------------------------------------
// K2 v10: byte-identical r13/r18 (j-pair, float2 stores; O ~= 27us, stable).
// The MFMA-epilogue variants (r19/r20) were BOTH racy under graph replay and
// slower (O ~= 39) — abandoned.
// ---------------------------------------------------------------------------
__global__ __launch_bounds__(256) void k_out(const float* __restrict__ x,
                                             const float* __restrict__ Ssum,
                                             const float* __restrict__ W,
                                             const float* __restrict__ b,
                                             const float* __restrict__ gamma,
                                             const float* __restrict__ beta,
                                             float* __restrict__ out) {
    const int n = blockIdx.x, tile = blockIdx.y;  // 15 tiles x 20 t
    const int tid = threadIdx.x;

    __shared__ __align__(16) float S_l[3*V_*ROWP];     // 2100
    __shared__ __align__(16) float xsh[TT2*C_*ROWP];   // 1680
    __shared__ __align__(16) float Wl[OUT_*12];        // 1152
    __shared__ __align__(8)  float2 so[OUT_];          // (scl, off) packed

    const float* xn = x + (size_t)n * C_*T_*V_;
    const int t0 = tile * TT2;
    const float inv_bn = rsqrtf(1.0f + 1e-5f);

    for (int i = tid; i < 3*V_*ROWP; i += 256) {
        const int s = i/(V_*ROWP), r = i%(V_*ROWP), v = r/ROWP, u = r%ROWP;
        S_l[i] = (u < V_) ? Ssum[(size_t)n*SEL + s*V_*V_ + v*V_ + u] : 0.f;
    }
    for (int i = tid; i < TT2*C_*ROWP; i += 256) {
        const int tt = i/(C_*ROWP), r = i%(C_*ROWP), c = r/ROWP, u = r%ROWP;
        xsh[i] = (u < V_) ? xn[c*(T_*V_) + (t0+tt)*V_ + u] : 0.f;
    }
    for (int i = tid; i < OUT_*12; i += 256) Wl[i] = W[i];
    if (tid < OUT_) {
        const float sc = gamma[tid] * inv_bn;
        so[tid] = make_float2(sc, b[tid]*sc + beta[tid]);
    }
    __syncthreads();

    if (tid < TT2*V_/2) {
        const int j0 = 2*tid, j1 = 2*tid + 1;
        const int tt0 = j0 / V_, iv0 = j0 % V_;
        const int tt1 = j1 / V_, iv1 = j1 % V_;
        const float* xb0 = &xsh[tt0*C_*ROWP];
        const float* xb1 = &xsh[tt1*C_*ROWP];

        float agg0[12], agg1[12];
        agg0[0] = (float)T_ * xb0[0*ROWP + iv0];
        agg0[1] = (float)T_ * xb0[1*ROWP + iv0];
        agg0[2] = (float)T_ * xb0[2*ROWP + iv0];
        agg1[0] = (float)T_ * xb1[0*ROWP + iv1];
        agg1[1] = (float)T_ * xb1[1*ROWP + iv1];
        agg1[2] = (float)T_ * xb1[2*ROWP + iv1];
        #pragma unroll
        for (int k = 3; k < 12; ++k) { agg0[k] = 0.f; agg1[k] = 0.f; }

        const float* Sr[3] = { &S_l[0*V_*ROWP], &S_l[1*V_*ROWP], &S_l[2*V_*ROWP] };
        #pragma unroll
        for (int u4 = 0; u4 < ROWP; u4 += 4) {
            const float4 p0 = *(const float4*)&xb0[0*ROWP + u4];
            const float4 p1 = *(const float4*)&xb0[1*ROWP + u4];
            const float4 p2 = *(const float4*)&xb0[2*ROWP + u4];
            const float4 q0 = *(const float4*)&xb1[0*ROWP + u4];
            const float4 q1 = *(const float4*)&xb1[1*ROWP + u4];
            const float4 q2 = *(const float4*)&xb1[2*ROWP + u4];
            #pragma unroll
            for (int s = 0; s < 3; ++s) {
                const float4 sa = *(const float4*)&Sr[s][iv0*ROWP + u4];
                const float4 sb = *(const float4*)&Sr[s][iv1*ROWP + u4];
                agg0[3*s+3] += sa.x*p0.x + sa.y*p0.y + sa.z*p0.z + sa.w*p0.w;
                agg0[3*s+4] += sa.x*p1.x + sa.y*p1.y + sa.z*p1.z + sa.w*p1.w;
                agg0[3*s+5] += sa.x*p2.x + sa.y*p2.y + sa.z*p2.z + sa.w*p2.w;
                agg1[3*s+3] += sb.x*q0.x + sb.y*q0.y + sb.z*q0.z + sb.w*q0.w;
                agg1[3*s+4] += sb.x*q1.x + sb.y*q1.y + sb.z*q1.z + sb.w*q1.w;
                agg1[3*s+5] += sb.x*q2.x + sb.y*q2.y + sb.z*q2.z + sb.w*q2.w;
            }
        }

        float* on = out + (size_t)n*(size_t)OUT_*T_*V_ + t0*V_ + j0;
        #pragma unroll 4
        for (int o = 0; o < OUT_; ++o) {
            const float4 w0 = *(const float4*)&Wl[o*12];
            const float4 w1 = *(const float4*)&Wl[o*12+4];
            const float4 w2 = *(const float4*)&Wl[o*12+8];
            const float2 s2 = so[o];
            float a0 = w0.x*agg0[0] + w0.y*agg0[1] + w0.z*agg0[2] + w0.w*agg0[3]
                     + w1.x*agg0[4] + w1.y*agg0[5] + w1.z*agg0[6] + w1.w*agg0[7]
                     + w2.x*agg0[8] + w2.y*agg0[9] + w2.z*agg0[10]+ w2.w*agg0[11];
            float a1 = w0.x*agg1[0] + w0.y*agg1[1] + w0.z*agg1[2] + w0.w*agg1[3]
                     + w1.x*agg1[4] + w1.y*agg1[5] + w1.z*agg1[6] + w1.w*agg1[7]
                     + w2.x*agg1[8] + w2.y*agg1[9] + w2.z*agg1[10]+ w2.w*agg1[11];
            float2 r;
            r.x = fmaxf(a0*s2.x + s2.y, 0.f);
            r.y = fmaxf(a1*s2.x + s2.y, 0.f);
            *(float2*)&on[(size_t)o*(T_*V_)] = r;
        }
    }
}

extern "C" void kernel_launch(void* const* d_in, const int* in_sizes, int n_in,
                              void* d_out, int out_size, void* d_ws, size_t ws_size,
                              hipStream_t stream) {
    const float* x     = (const float*)d_in[0];
    const float* xx    = (const float*)d_in[1];
    const float* W     = (const float*)d_in[2];
    const float* b     = (const float*)d_in[3];
    const float* gamma = (const float*)d_in[4];
    const float* beta  = (const float*)d_in[5];
    float* out  = (float*)d_out;

    float* Ssum    = (float*)d_ws;                  // 240 KB
    float* partial = (float*)d_ws + (size_t)N_*SEL; // 14.4 MB (60 recs/n)

    k_powsum<<<dim3(N_, 15), 256, 0, stream>>>(xx, partial);
    k_reduce<<<(N_*SEL + 255)/256, 256, 0, stream>>>(partial, Ssum);
    k_out   <<<dim3(N_, T_/TT2), 256, 0, stream>>>(x, Ssum, W, b, gamma, beta, out);
}